// Round 1
// baseline (268.437 us; speedup 1.0000x reference)
//
#include <hip/hip_runtime.h>
#include <hip/hip_bf16.h>

#define BATCH  512
#define TT     16
#define NN     22
#define CC     64
#define DD     1024          // TT*CC
#define NB     3
#define XSTR   1028          // padded LDS row stride (floats), multiple of 4
#define NPAIR  253           // 22*23/2
#define NTHR   512

__global__ __launch_bounds__(NTHR) void mbdsca_fused(
    const float* __restrict__ x,        // [B, T, N, C]
    const float* __restrict__ adj,      // [N, N]
    const float* __restrict__ btemps,   // [NB]
    const float* __restrict__ flogits,  // [2, NB]
    float* __restrict__ out)            // [B*N*D] xb  ++  [N*N] A
{
  __shared__ float xs[NN][XSTR];        // 90.4 KB: current xb
  __shared__ float As[NN][NN];
  __shared__ float Gs[NN][NN];
  __shared__ float Ws[NN][NN];
  __shared__ float norms[NN];
  __shared__ float alphas[2][NB];
  __shared__ float tvals[NB];

  const int tid = threadIdx.x;
  const int b   = blockIdx.x;

  // ---------- region 1: raw a = clip(clip(adj,0,1)+I, 1e-8, inf); temps ----------
  if (tid < NN * NN) {
    int n = tid / NN, m = tid - n * NN;
    float v = adj[tid];
    v = fminf(fmaxf(v, 0.0f), 1.0f);
    if (n == m) v += 1.0f;
    v = fmaxf(v, 1e-8f);
    As[n][m] = v;
  }
  if (tid < NB) tvals[tid] = fminf(fmaxf(btemps[tid], 0.1f), 10.0f);
  __syncthreads();

  // ---------- region 2: degree d = clip(rowsum^-0.5, 0, 100); fusion alphas ----------
  if (tid < NN) {
    float s = 0.0f;
    for (int m = 0; m < NN; ++m) s += As[tid][m];
    s = fmaxf(s, 1e-8f);
    norms[tid] = fminf(fmaxf(1.0f / sqrtf(s), 0.0f), 100.0f);
  }
  if (tid == 0) {
    for (int l = 0; l < 2; ++l) {
      float l0 = flogits[l*NB+0], l1 = flogits[l*NB+1], l2 = flogits[l*NB+2];
      float mx = fmaxf(l0, fmaxf(l1, l2));
      float e0 = __expf(l0-mx), e1 = __expf(l1-mx), e2 = __expf(l2-mx);
      float s = e0 + e1 + e2;
      alphas[l][0] = e0/s; alphas[l][1] = e1/s; alphas[l][2] = e2/s;
    }
  }
  __syncthreads();

  // ---------- region 3: A = d_n * a * d_m; stage x0 into LDS ----------
  if (tid < NN * NN) {
    int n = tid / NN, m = tid - n * NN;
    As[n][m] = norms[n] * As[n][m] * norms[m];
  }
  for (int g = tid; g < TT * NN * CC; g += NTHR) {
    int t = g / (NN * CC);
    int r = g - t * (NN * CC);
    int n = r >> 6;          // /CC
    int c = r & 63;          // %CC
    xs[n][t * CC + c] = x[b * (TT * NN * CC) + g];   // coalesced global read
  }
  __syncthreads();

  // ---------- two GNN layers ----------
  for (int layer = 0; layer < 2; ++layer) {
    const int K = (layer == 0) ? 10 : 3;

    // --- Gram: 2 lanes per (n<=m) pair, float4 LDS reads ---
    {
      int p = tid >> 1;
      int e = tid & 1;
      if (p < NPAIR) {
        int n = 0, rem = p;
        while (rem >= NN - n) { rem -= NN - n; ++n; }
        int m = n + rem;
        const float4* rn = (const float4*)(&xs[n][e * 512]);
        const float4* rm = (const float4*)(&xs[m][e * 512]);
        float acc = 0.0f;
        #pragma unroll 8
        for (int i = 0; i < 128; ++i) {
          float4 a = rn[i], c = rm[i];
          acc += a.x*c.x; acc += a.y*c.y; acc += a.z*c.z; acc += a.w*c.w;
        }
        acc += __shfl_xor(acc, 1);
        if (e == 0) { Gs[n][m] = acc; Gs[m][n] = acc; }
      }
    }
    __syncthreads();

    if (tid < NN) norms[tid] = sqrtf(Gs[tid][tid]) + 1e-6f;
    __syncthreads();

    // --- sim = cos * A ---
    if (tid < NN * NN) {
      int n = tid / NN, m = tid - n * NN;
      Gs[n][m] = Gs[n][m] / (norms[n] * norms[m]) * As[n][m];
    }
    __syncthreads();

    // --- combined branch weights: W[n][:] = sum_k alpha_k * softmax(topK(att_k)) ---
    if (tid < NN) {
      const int n = tid;
      for (int m = 0; m < NN; ++m) Ws[n][m] = 0.0f;
      for (int k = 0; k < NB; ++k) {
        const float tk = tvals[k];
        const float ak = alphas[layer][k];
        unsigned sel = 0u;
        for (int kk = 0; kk < K; ++kk) {           // lax.top_k: lower index wins ties
          float best = -1e30f; int bi = 0;
          for (int m = 0; m < NN; ++m) {
            if (sel & (1u << m)) continue;
            float v = Gs[n][m] / tk + ((m == n) ? 0.1f : 0.0f);
            if (v > best) { best = v; bi = m; }
          }
          sel |= 1u << bi;
        }
        // softmax over att*mask: non-selected entries are exact 0 and participate
        float mx = -1e30f;
        for (int m = 0; m < NN; ++m) {
          float v = (sel & (1u << m)) ? (Gs[n][m] / tk + ((m == n) ? 0.1f : 0.0f)) : 0.0f;
          mx = fmaxf(mx, v);
        }
        float ssum = 0.0f;
        for (int m = 0; m < NN; ++m) {
          float v = (sel & (1u << m)) ? (Gs[n][m] / tk + ((m == n) ? 0.1f : 0.0f)) : 0.0f;
          ssum += __expf(v - mx);
        }
        float sc = ak / ssum;
        for (int m = 0; m < NN; ++m) {
          float v = (sel & (1u << m)) ? (Gs[n][m] / tk + ((m == n) ? 0.1f : 0.0f)) : 0.0f;
          Ws[n][m] += __expf(v - mx) * sc;
        }
      }
    }
    __syncthreads();

    // --- aggregation: acc[n][d] = sum_m W[n][m] * xs[m][d] (float4 over d) ---
    float4 acc[11];                       // 22528/4/512 = 11 float4 per thread
    #pragma unroll
    for (int j = 0; j < 11; ++j) {
      int g4 = tid + j * NTHR;            // float4 index in [0, 5632)
      int n  = g4 >> 8;                   // / 256
      int d4 = g4 & 255;
      float4 a = make_float4(0.f, 0.f, 0.f, 0.f);
      #pragma unroll
      for (int m = 0; m < NN; ++m) {
        float w = Ws[n][m];
        const float4 v = *(const float4*)(&xs[m][d4 * 4]);
        a.x += w * v.x; a.y += w * v.y; a.z += w * v.z; a.w += w * v.w;
      }
      acc[j] = a;
    }
    __syncthreads();                      // all xs reads complete

    if (layer == 0) {
      #pragma unroll
      for (int j = 0; j < 11; ++j) {
        int g4 = tid + j * NTHR;
        int n  = g4 >> 8;
        int d4 = g4 & 255;
        float4 a = acc[j];
        a.x = fmaxf(a.x, 0.f); a.y = fmaxf(a.y, 0.f);
        a.z = fmaxf(a.z, 0.f); a.w = fmaxf(a.w, 0.f);
        *(float4*)(&xs[n][d4 * 4]) = a;   // xb <- relu(W @ xb)
      }
    } else {
      #pragma unroll
      for (int j = 0; j < 11; ++j) {
        int g4 = tid + j * NTHR;
        int n  = g4 >> 8;
        int d4 = g4 & 255;
        // residual x0[b,n,d]: d = d4*4, t = d4>>4, c = (d4&15)*4
        const float4 x0v = *(const float4*)(
            &x[b * (TT*NN*CC) + (d4 >> 4) * (NN*CC) + n * CC + (d4 & 15) * 4]);
        float4 a = acc[j];
        a.x += x0v.x; a.y += x0v.y; a.z += x0v.z; a.w += x0v.w;
        *(float4*)(&out[(size_t)b * (NN*DD) + (size_t)g4 * 4]) = a;
      }
    }
    __syncthreads();
  }

  // ---------- A output (second tuple element) ----------
  if (b == 0 && tid < NN * NN) {
    out[(size_t)BATCH * NN * DD + tid] = As[tid / NN][tid - (tid / NN) * NN];
  }
}

extern "C" void kernel_launch(void* const* d_in, const int* in_sizes, int n_in,
                              void* d_out, int out_size, void* d_ws, size_t ws_size,
                              hipStream_t stream) {
  const float* x       = (const float*)d_in[0];
  const float* adj     = (const float*)d_in[1];
  const float* btemps  = (const float*)d_in[2];
  const float* flogits = (const float*)d_in[3];
  float* out = (float*)d_out;
  mbdsca_fused<<<BATCH, NTHR, 0, stream>>>(x, adj, btemps, flogits, out);
}

// Round 2
// 150.026 us; speedup vs baseline: 1.7893x; 1.7893x over previous
//
#include <hip/hip_runtime.h>
#include <hip/hip_bf16.h>

#define BATCH  512
#define TT     16
#define NN     22
#define CC     64
#define DD     1024          // TT*CC
#define NB     3
#define XS     1032          // bf16 LDS row stride: rowstride 2064B -> bank = 4*row mod 32 (2-way, free)
#define NTHR   512

typedef __bf16 bf16x8 __attribute__((ext_vector_type(8)));
typedef float  f32x4  __attribute__((ext_vector_type(4)));

__device__ __forceinline__ unsigned bf16rne(float x) {
  unsigned u = __float_as_uint(x);
  u += 0x7fffu + ((u >> 16) & 1u);
  return u >> 16;
}
__device__ __forceinline__ unsigned pack2(float a, float b) {
  return bf16rne(a) | (bf16rne(b) << 16);
}
__device__ __forceinline__ void unpack8(uint4 u, float f[8]) {
  f[0] = __uint_as_float(u.x << 16); f[1] = __uint_as_float(u.x & 0xffff0000u);
  f[2] = __uint_as_float(u.y << 16); f[3] = __uint_as_float(u.y & 0xffff0000u);
  f[4] = __uint_as_float(u.z << 16); f[5] = __uint_as_float(u.z & 0xffff0000u);
  f[6] = __uint_as_float(u.w << 16); f[7] = __uint_as_float(u.w & 0xffff0000u);
}

__global__ __launch_bounds__(NTHR, 4) void mbdsca_fused(
    const float* __restrict__ x,        // [B, T, N, C]
    const float* __restrict__ adj,      // [N, N]
    const float* __restrict__ btemps,   // [NB]
    const float* __restrict__ flogits,  // [2, NB]
    float* __restrict__ out)            // [B*N*D] xb  ++  [N*N] A
{
  __shared__ unsigned short xs[NN][XS];   // 45.4 KB: current xb in bf16
  __shared__ float As[NN][NN];
  __shared__ float Gs[NN][NN];
  __shared__ float Ws[NN][NN];
  __shared__ float attA[NB][NN][NN];
  __shared__ float attB[NB][NN][NN];
  __shared__ float norms[NN];
  __shared__ float alphas[2][NB];
  __shared__ float tvals[NB];

  const int tid = threadIdx.x;
  const int b   = blockIdx.x;
  const int lane = tid & 63;
  const int wv   = tid >> 6;

  // ---------- region 1: raw a = clip(clip(adj,0,1)+I, 1e-8, inf); temps ----------
  if (tid < NN * NN) {
    int n = tid / NN, m = tid - n * NN;
    float v = adj[tid];
    v = fminf(fmaxf(v, 0.0f), 1.0f);
    if (n == m) v += 1.0f;
    v = fmaxf(v, 1e-8f);
    As[n][m] = v;
  }
  if (tid < NB) tvals[tid] = fminf(fmaxf(btemps[tid], 0.1f), 10.0f);
  __syncthreads();

  // ---------- region 2: degree d = clip(rowsum^-0.5, 0, 100); fusion alphas ----------
  if (tid < NN) {
    float s = 0.0f;
    for (int m = 0; m < NN; ++m) s += As[tid][m];
    s = fmaxf(s, 1e-8f);
    norms[tid] = fminf(fmaxf(1.0f / sqrtf(s), 0.0f), 100.0f);
  }
  if (tid == 0) {
    for (int l = 0; l < 2; ++l) {
      float l0 = flogits[l*NB+0], l1 = flogits[l*NB+1], l2 = flogits[l*NB+2];
      float mx = fmaxf(l0, fmaxf(l1, l2));
      float e0 = __expf(l0-mx), e1 = __expf(l1-mx), e2 = __expf(l2-mx);
      float s = e0 + e1 + e2;
      alphas[l][0] = e0/s; alphas[l][1] = e1/s; alphas[l][2] = e2/s;
    }
  }
  __syncthreads();

  // ---------- region 3: A = d_n * a * d_m; stage x0 into LDS as bf16 ----------
  if (tid < NN * NN) {
    int n = tid / NN, m = tid - n * NN;
    As[n][m] = norms[n] * As[n][m] * norms[m];
  }
  // 5632 float4s of x; convert to bf16 pairs, ds_write_b64
  #pragma unroll
  for (int j = 0; j < 11; ++j) {
    int f4  = tid + j * NTHR;
    int t   = f4 / (NN * (CC/4));
    int rem = f4 - t * (NN * (CC/4));
    int n   = rem >> 4;
    int c4  = rem & 15;
    const float4 v = *(const float4*)(&x[(size_t)b * (TT*NN*CC) + (size_t)f4 * 4]);
    uint2 p; p.x = pack2(v.x, v.y); p.y = pack2(v.z, v.w);
    *(uint2*)(&xs[n][t * CC + c4 * 4]) = p;
  }
  __syncthreads();

  // ---------- two GNN layers ----------
  for (int layer = 0; layer < 2; ++layer) {
    const int K = (layer == 0) ? 10 : 3;

    // --- P1 Gram via MFMA: G = X * X^T, 2x2 tiles of 16, K=1024 (32 steps) ---
    if (wv < 4) {
      const int Mt = wv >> 1, Nt = wv & 1;
      int arow = Mt * 16 + (lane & 15); if (arow > NN-1) arow = NN-1;
      int brow = Nt * 16 + (lane & 15); if (brow > NN-1) brow = NN-1;
      const int koff = (lane >> 4) * 8;
      f32x4 acc = {0.f, 0.f, 0.f, 0.f};
      #pragma unroll 4
      for (int ks = 0; ks < 32; ++ks) {
        bf16x8 a = *reinterpret_cast<const bf16x8*>(&xs[arow][ks * 32 + koff]);
        bf16x8 bb = *reinterpret_cast<const bf16x8*>(&xs[brow][ks * 32 + koff]);
        acc = __builtin_amdgcn_mfma_f32_16x16x32_bf16(a, bb, acc, 0, 0, 0);
      }
      #pragma unroll
      for (int r = 0; r < 4; ++r) {
        int row = Mt * 16 + (lane >> 4) * 4 + r;
        int col = Nt * 16 + (lane & 15);
        if (row < NN && col < NN) Gs[row][col] = acc[r];
      }
    }
    __syncthreads();

    // --- P2 cos norms from diagonal ---
    if (tid < NN) norms[tid] = sqrtf(Gs[tid][tid]) + 1e-6f;
    __syncthreads();

    // --- P3 sim = cos * A (each thread owns one element) ---
    if (tid < NN * NN) {
      int n = tid / NN, m = tid - n * NN;
      Gs[n][m] = Gs[n][m] / (norms[n] * norms[m]) * As[n][m];
    }
    __syncthreads();

    // --- P4 per-branch logits: attA[k][n][m] = sim/tk + 0.1*I ---
    for (int q = tid; q < NB * NN * NN; q += NTHR) {
      int k = q / (NN*NN), r = q - k * (NN*NN);
      int n = r / NN, m = r - n * NN;
      attA[k][n][m] = Gs[n][m] / tvals[k] + ((n == m) ? 0.1f : 0.0f);
    }
    __syncthreads();

    // --- P5 top-K mask via rank (lax.top_k: ties -> lowest index wins) ---
    for (int q = tid; q < NB * NN * NN; q += NTHR) {
      int k = q / (NN*NN), r = q - k * (NN*NN);
      int n = r / NN, m = r - n * NN;
      float v = attA[k][n][m];
      int rank = 0;
      #pragma unroll
      for (int j = 0; j < NN; ++j) {
        float vj = attA[k][n][j];
        rank += (vj > v) || (vj == v && j < m);
      }
      attB[k][n][m] = (rank < K) ? v : 0.0f;   // zeros still join the softmax
    }
    __syncthreads();

    // --- P6 row softmax * alpha, in place (thread owns row) ---
    if (tid < NB * NN) {
      int k = tid / NN, n = tid - k * NN;
      float mx = -1e30f;
      for (int m = 0; m < NN; ++m) mx = fmaxf(mx, attB[k][n][m]);
      float s = 0.0f;
      for (int m = 0; m < NN; ++m) s += __expf(attB[k][n][m] - mx);
      float sc = alphas[layer][k] / s;
      for (int m = 0; m < NN; ++m) attB[k][n][m] = __expf(attB[k][n][m] - mx) * sc;
    }
    __syncthreads();

    // --- P7 combined weights ---
    if (tid < NN * NN) {
      int n = tid / NN, m = tid - n * NN;
      Ws[n][m] = attB[0][n][m] + attB[1][n][m] + attB[2][n][m];
    }
    __syncthreads();

    // --- P8 aggregation: out[n][d] = sum_m W[n][m]*xs[m][d]; 2 rows x 8 cols/thread ---
    if (layer == 0) {
      unsigned packed[3][8];
      #pragma unroll
      for (int it = 0; it < 3; ++it) {
        int task = tid + it * NTHR;
        if (task < 11 * 128) {
          int np = task >> 7, d8 = task & 127;
          int n0 = np * 2, n1 = n0 + 1, e0 = d8 * 8;
          float a0[8] = {0,0,0,0,0,0,0,0}, a1[8] = {0,0,0,0,0,0,0,0}, f[8];
          for (int m = 0; m < NN; ++m) {
            float w0 = Ws[n0][m], w1 = Ws[n1][m];
            uint4 u = *(const uint4*)(&xs[m][e0]);
            unpack8(u, f);
            #pragma unroll
            for (int j = 0; j < 8; ++j) { a0[j] += w0 * f[j]; a1[j] += w1 * f[j]; }
          }
          #pragma unroll
          for (int j = 0; j < 8; ++j) { a0[j] = fmaxf(a0[j], 0.f); a1[j] = fmaxf(a1[j], 0.f); }
          #pragma unroll
          for (int j = 0; j < 4; ++j) {
            packed[it][j]     = pack2(a0[2*j], a0[2*j+1]);
            packed[it][j + 4] = pack2(a1[2*j], a1[2*j+1]);
          }
        }
      }
      __syncthreads();            // all reads of xs complete
      #pragma unroll
      for (int it = 0; it < 3; ++it) {
        int task = tid + it * NTHR;
        if (task < 11 * 128) {
          int np = task >> 7, d8 = task & 127;
          int n0 = np * 2, n1 = n0 + 1, e0 = d8 * 8;
          *(uint4*)(&xs[n0][e0]) = make_uint4(packed[it][0], packed[it][1], packed[it][2], packed[it][3]);
          *(uint4*)(&xs[n1][e0]) = make_uint4(packed[it][4], packed[it][5], packed[it][6], packed[it][7]);
        }
      }
      __syncthreads();            // xb updated for layer 1
    } else {
      #pragma unroll
      for (int it = 0; it < 3; ++it) {
        int task = tid + it * NTHR;
        if (task < 11 * 128) {
          int np = task >> 7, d8 = task & 127;
          int n0 = np * 2, n1 = n0 + 1, e0 = d8 * 8;
          float a0[8] = {0,0,0,0,0,0,0,0}, a1[8] = {0,0,0,0,0,0,0,0}, f[8];
          for (int m = 0; m < NN; ++m) {
            float w0 = Ws[n0][m], w1 = Ws[n1][m];
            uint4 u = *(const uint4*)(&xs[m][e0]);
            unpack8(u, f);
            #pragma unroll
            for (int j = 0; j < 8; ++j) { a0[j] += w0 * f[j]; a1[j] += w1 * f[j]; }
          }
          // residual x0 (f32 from global) + write out
          int t = e0 >> 6, c = e0 & 63;
          const float* xb0 = &x[(((size_t)b * TT + t) * NN) * CC + c];
          const float4 r00 = *(const float4*)(xb0 + n0 * CC);
          const float4 r01 = *(const float4*)(xb0 + n0 * CC + 4);
          const float4 r10 = *(const float4*)(xb0 + n1 * CC);
          const float4 r11 = *(const float4*)(xb0 + n1 * CC + 4);
          float* o0 = &out[((size_t)b * NN + n0) * DD + e0];
          float* o1 = &out[((size_t)b * NN + n1) * DD + e0];
          *(float4*)(o0)     = make_float4(a0[0]+r00.x, a0[1]+r00.y, a0[2]+r00.z, a0[3]+r00.w);
          *(float4*)(o0 + 4) = make_float4(a0[4]+r01.x, a0[5]+r01.y, a0[6]+r01.z, a0[7]+r01.w);
          *(float4*)(o1)     = make_float4(a1[0]+r10.x, a1[1]+r10.y, a1[2]+r10.z, a1[3]+r10.w);
          *(float4*)(o1 + 4) = make_float4(a1[4]+r11.x, a1[5]+r11.y, a1[6]+r11.z, a1[7]+r11.w);
        }
      }
    }
  }

  // ---------- A output (second tuple element) ----------
  if (b == 0 && tid < NN * NN) {
    out[(size_t)BATCH * NN * DD + tid] = As[tid / NN][tid - (tid / NN) * NN];
  }
}

extern "C" void kernel_launch(void* const* d_in, const int* in_sizes, int n_in,
                              void* d_out, int out_size, void* d_ws, size_t ws_size,
                              hipStream_t stream) {
  const float* x       = (const float*)d_in[0];
  const float* adj     = (const float*)d_in[1];
  const float* btemps  = (const float*)d_in[2];
  const float* flogits = (const float*)d_in[3];
  float* out = (float*)d_out;
  mbdsca_fused<<<BATCH, NTHR, 0, stream>>>(x, adj, btemps, flogits, out);
}

// Round 3
// 57.170 us; speedup vs baseline: 4.6954x; 2.6242x over previous
//
#include <hip/hip_runtime.h>
#include <hip/hip_bf16.h>

#define BATCH  512
#define TT     16
#define NN     22
#define CC     64
#define DD     1024          // TT*CC
#define NB     3
#define XS     1032          // bf16 LDS row stride: 2064B row -> bank period 8 rows (2-way on b128, free)
#define NTHR   512

typedef __bf16 bf16x8 __attribute__((ext_vector_type(8)));
typedef float  f32x4  __attribute__((ext_vector_type(4)));

__device__ __forceinline__ unsigned bf16rne(float x) {
  unsigned u = __float_as_uint(x);
  u += 0x7fffu + ((u >> 16) & 1u);
  return u >> 16;
}
__device__ __forceinline__ unsigned pack2(float a, float b) {
  return bf16rne(a) | (bf16rne(b) << 16);
}

__global__ __launch_bounds__(NTHR) void mbdsca_fused(
    const float* __restrict__ x,        // [B, T, N, C]
    const float* __restrict__ adj,      // [N, N]
    const float* __restrict__ btemps,   // [NB]
    const float* __restrict__ flogits,  // [2, NB]
    float* __restrict__ out)            // [B*N*D] xb  ++  [N*N] A
{
  __shared__ unsigned short xs[NN][XS];   // 45.4 KB: current xb in bf16
  __shared__ float As[NN][NN];
  __shared__ float Gs[NN][NN];
  __shared__ float Ws[NN][NN];
  __shared__ float attB[NB][NN][NN];
  __shared__ float norms[NN];
  __shared__ float alphas[2][NB];
  __shared__ float tvals[NB];

  const int tid = threadIdx.x;
  const int b   = blockIdx.x;
  const int lane = tid & 63;
  const int wv   = tid >> 6;

  // ---------- region 1: raw a = clip(clip(adj,0,1)+I, 1e-8, inf); temps ----------
  if (tid < NN * NN) {
    int n = tid / NN, m = tid - n * NN;
    float v = adj[tid];
    v = fminf(fmaxf(v, 0.0f), 1.0f);
    if (n == m) v += 1.0f;
    v = fmaxf(v, 1e-8f);
    As[n][m] = v;
  }
  if (tid < NB) tvals[tid] = fminf(fmaxf(btemps[tid], 0.1f), 10.0f);
  __syncthreads();

  // ---------- region 2: degree d = clip(rowsum^-0.5, 0, 100); fusion alphas ----------
  if (tid < NN) {
    float s = 0.0f;
    for (int m = 0; m < NN; ++m) s += As[tid][m];
    s = fmaxf(s, 1e-8f);
    norms[tid] = fminf(fmaxf(1.0f / sqrtf(s), 0.0f), 100.0f);
  }
  if (tid == 0) {
    for (int l = 0; l < 2; ++l) {
      float l0 = flogits[l*NB+0], l1 = flogits[l*NB+1], l2 = flogits[l*NB+2];
      float mx = fmaxf(l0, fmaxf(l1, l2));
      float e0 = __expf(l0-mx), e1 = __expf(l1-mx), e2 = __expf(l2-mx);
      float s = e0 + e1 + e2;
      alphas[l][0] = e0/s; alphas[l][1] = e1/s; alphas[l][2] = e2/s;
    }
  }
  __syncthreads();

  // ---------- region 3: A = d_n * a * d_m; stage x0 into LDS as bf16 ----------
  if (tid < NN * NN) {
    int n = tid / NN, m = tid - n * NN;
    As[n][m] = norms[n] * As[n][m] * norms[m];
  }
  #pragma unroll
  for (int j = 0; j < 11; ++j) {
    int f4  = tid + j * NTHR;                 // float4 index into x[b]
    int t   = f4 / (NN * (CC/4));
    int rem = f4 - t * (NN * (CC/4));
    int n   = rem >> 4;
    int c4  = rem & 15;
    const float4 v = *(const float4*)(&x[(size_t)b * (TT*NN*CC) + (size_t)f4 * 4]);
    uint2 p; p.x = pack2(v.x, v.y); p.y = pack2(v.z, v.w);
    *(uint2*)(&xs[n][t * CC + c4 * 4]) = p;
  }
  __syncthreads();

  // ---------- two GNN layers ----------
  for (int layer = 0; layer < 2; ++layer) {
    const int K = (layer == 0) ? 10 : 3;

    // --- P1 Gram via MFMA: G = X * X^T, 2x2 tiles of 16, K=1024 (32 steps) ---
    if (wv < 4) {
      const int Mt = wv >> 1, Nt = wv & 1;
      int arow = Mt * 16 + (lane & 15); if (arow > NN-1) arow = NN-1;
      int brow = Nt * 16 + (lane & 15); if (brow > NN-1) brow = NN-1;
      const int koff = (lane >> 4) * 8;
      f32x4 acc = {0.f, 0.f, 0.f, 0.f};
      #pragma unroll 4
      for (int ks = 0; ks < 32; ++ks) {
        bf16x8 a = *reinterpret_cast<const bf16x8*>(&xs[arow][ks * 32 + koff]);
        bf16x8 bb = *reinterpret_cast<const bf16x8*>(&xs[brow][ks * 32 + koff]);
        acc = __builtin_amdgcn_mfma_f32_16x16x32_bf16(a, bb, acc, 0, 0, 0);
      }
      #pragma unroll
      for (int r = 0; r < 4; ++r) {
        int row = Mt * 16 + (lane >> 4) * 4 + r;
        int col = Nt * 16 + (lane & 15);
        if (row < NN && col < NN) Gs[row][col] = acc[r];
      }
    }
    __syncthreads();

    // --- P2 cos norms from diagonal ---
    if (tid < NN) norms[tid] = sqrtf(Gs[tid][tid]) + 1e-6f;
    __syncthreads();

    // --- P3 sim = cos * A (each thread owns one element) ---
    if (tid < NN * NN) {
      int n = tid / NN, m = tid - n * NN;
      Gs[n][m] = Gs[n][m] / (norms[n] * norms[m]) * As[n][m];
    }
    __syncthreads();

    // --- P5 top-K mask via rank (lax.top_k: ties -> lowest index wins) ---
    for (int q = tid; q < NB * NN * NN; q += NTHR) {
      int k = q / (NN*NN), r = q - k * (NN*NN);
      int n = r / NN, m = r - n * NN;
      const float rtk = 1.0f / tvals[k];
      float v = Gs[n][m] * rtk + ((n == m) ? 0.1f : 0.0f);
      int rank = 0;
      #pragma unroll
      for (int j = 0; j < NN; ++j) {
        float vj = Gs[n][j] * rtk + ((n == j) ? 0.1f : 0.0f);
        rank += (vj > v) || (vj == v && j < m);
      }
      attB[k][n][m] = (rank < K) ? v : 0.0f;   // zeros still join the softmax
    }
    __syncthreads();

    // --- P6 row softmax * alpha, in place (thread owns row) ---
    if (tid < NB * NN) {
      int k = tid / NN, n = tid - k * NN;
      float mx = -1e30f;
      for (int m = 0; m < NN; ++m) mx = fmaxf(mx, attB[k][n][m]);
      float s = 0.0f;
      for (int m = 0; m < NN; ++m) s += __expf(attB[k][n][m] - mx);
      float sc = alphas[layer][k] / s;
      for (int m = 0; m < NN; ++m) attB[k][n][m] = __expf(attB[k][n][m] - mx) * sc;
    }
    __syncthreads();

    // --- P7 combined weights ---
    if (tid < NN * NN) {
      int n = tid / NN, m = tid - n * NN;
      Ws[n][m] = attB[0][n][m] + attB[1][n][m] + attB[2][n][m];
    }
    __syncthreads();

    // --- P8 aggregation: acc[n][d] = sum_m W[n][m]*xs[m][d]; 11 x (1 row, 4 cols)/thread ---
    // All indices compile-time after unroll: acc stays in VGPRs (no scratch).
    f32x4 acc[11];
    #pragma unroll
    for (int j = 0; j < 11; ++j) {
      const int g4 = tid + j * NTHR;     // 0..5631 ; n uniform per wave
      const int n  = g4 >> 8;
      const int d4 = g4 & 255;
      f32x4 a = {0.f, 0.f, 0.f, 0.f};
      for (int m = 0; m < NN; ++m) {
        const float w = Ws[n][m];
        const uint2 u = *(const uint2*)(&xs[m][d4 * 4]);
        a[0] += w * __uint_as_float(u.x << 16);
        a[1] += w * __uint_as_float(u.x & 0xffff0000u);
        a[2] += w * __uint_as_float(u.y << 16);
        a[3] += w * __uint_as_float(u.y & 0xffff0000u);
      }
      acc[j] = a;
    }
    __syncthreads();                      // all xs reads complete

    if (layer == 0) {
      #pragma unroll
      for (int j = 0; j < 11; ++j) {
        const int g4 = tid + j * NTHR;
        const int n  = g4 >> 8;
        const int d4 = g4 & 255;
        f32x4 a = acc[j];
        uint2 p;
        p.x = pack2(fmaxf(a[0], 0.f), fmaxf(a[1], 0.f));
        p.y = pack2(fmaxf(a[2], 0.f), fmaxf(a[3], 0.f));
        *(uint2*)(&xs[n][d4 * 4]) = p;    // xb <- relu(W @ xb)
      }
      __syncthreads();
    } else {
      #pragma unroll
      for (int j = 0; j < 11; ++j) {
        const int g4 = tid + j * NTHR;
        const int n  = g4 >> 8;
        const int d4 = g4 & 255;
        // residual x0[b, t=d4>>4, n, c=(d4&15)*4] in f32 from global (L3-resident)
        const float4 r = *(const float4*)(
            &x[(size_t)b * (TT*NN*CC) + (size_t)(d4 >> 4) * (NN*CC) + n * CC + (d4 & 15) * 4]);
        f32x4 a = acc[j];
        *(float4*)(&out[((size_t)b * NN + n) * DD + d4 * 4]) =
            make_float4(a[0] + r.x, a[1] + r.y, a[2] + r.z, a[3] + r.w);
      }
    }
  }

  // ---------- A output (second tuple element) ----------
  if (b == 0 && tid < NN * NN) {
    out[(size_t)BATCH * NN * DD + tid] = As[tid / NN][tid - (tid / NN) * NN];
  }
}

extern "C" void kernel_launch(void* const* d_in, const int* in_sizes, int n_in,
                              void* d_out, int out_size, void* d_ws, size_t ws_size,
                              hipStream_t stream) {
  const float* x       = (const float*)d_in[0];
  const float* adj     = (const float*)d_in[1];
  const float* btemps  = (const float*)d_in[2];
  const float* flogits = (const float*)d_in[3];
  float* out = (float*)d_out;
  mbdsca_fused<<<BATCH, NTHR, 0, stream>>>(x, adj, btemps, flogits, out);
}